// Round 6
// baseline (120.584 us; speedup 1.0000x reference)
//
#include <hip/hip_runtime.h>

#define IMG_W 2048
#define NUM_NODES 255
#define NLEAF 128
#define DEPTH 7
#define RS 68    // padded LDS row stride (floats); 16B-chunk bank-group = (row+q)%8 -> balanced
#define NBLK 256 // one block per CU, co-resident by construction (105KB LDS -> 1/CU)

// DPP xor-butterfly add over 16-lane groups (VALU pipe). Butterfly partners add
// identical pairs -> all 16 lanes end bit-identical.
template<int CTRL>
__device__ __forceinline__ float dpp_add(float x) {
    int v = __builtin_amdgcn_update_dpp(0, __float_as_int(x), CTRL, 0xF, 0xF, true);
    return x + __int_as_float(v);
}
__device__ __forceinline__ float group16_sum(float x) {
    x = dpp_add<0xB1>(x);   // quad_perm [1,0,3,2]  : xor 1
    x = dpp_add<0x4E>(x);   // quad_perm [2,3,0,1]  : xor 2
    x = dpp_add<0x141>(x);  // row_half_mirror      : xor 7
    x = dpp_add<0x128>(x);  // row_ror:8            : xor 8
    return x;
}

// ---- K1: 4-way interleaved descent + LDS accumulate + PARALLEL fused update --
// R3 fusion failed because the tail ran 255 nodes on 16 CUs (~8-10us serial).
// R6 fix: ALL blocks participate, ONE node per block (tail ~0.6us/CU, parallel);
// only wave 0 polls fdone (s_sleep backoff), other waves park at s_barrier.
// Descent/accumulate/flush = exact R2 (R4 transpose + R5 reg-cache reverted,
// both measured neutral-to-negative).
__global__ __launch_bounds__(1024, 4) void fusedK(const float* __restrict__ img,
                                                  const float* __restrict__ nodes,
                                                  float* __restrict__ leaf_out,
                                                  float* __restrict__ S,
                                                  unsigned* __restrict__ cnt,
                                                  unsigned* __restrict__ fdone,
                                                  float* __restrict__ out_nodes)
{
    __shared__ float nds[NUM_NODES * RS];   // 69360 B (reused as S-stage in tail)
    __shared__ float Sl[NLEAF * RS];        // 34816 B
    __shared__ unsigned cntl[NLEAF];

    const int t = threadIdx.x;
    const int b = blockIdx.x;
    const int g = t >> 4;          // patch-group 0..63
    const int q = t & 15;          // quad within patch (elements 4q..4q+3)
    const int q4 = q * 4;

    for (int i = t; i < NLEAF * RS; i += 1024) Sl[i] = 0.0f;
    if (t < NLEAF) cntl[t] = 0u;

    // fill node table (padded rows)
    const float4* ng = (const float4*)nodes;
    for (int i = t; i < NUM_NODES * 16; i += 1024) {
        *(float4*)&nds[(i >> 4) * RS + (i & 15) * 4] = ng[i];
    }

    // prefetch 4 chunks' patch quads (element e=4q+j -> pixel (q>>1, (q&1)*4+j))
    float4 xv0, xv1, xv2, xv3;
    {
        const int roff = (q >> 1), coff = (q & 1) * 4;
        int p = b * 256 + g;
        xv0 = *(const float4*)(img + (size_t)((p >> 8) * 8 + roff) * IMG_W + (p & 255) * 8 + coff);
        p += 64;
        xv1 = *(const float4*)(img + (size_t)((p >> 8) * 8 + roff) * IMG_W + (p & 255) * 8 + coff);
        p += 64;
        xv2 = *(const float4*)(img + (size_t)((p >> 8) * 8 + roff) * IMG_W + (p & 255) * 8 + coff);
        p += 64;
        xv3 = *(const float4*)(img + (size_t)((p >> 8) * 8 + roff) * IMG_W + (p & 255) * 8 + coff);
    }
    __syncthreads();

    // 4 interleaved descents
    int cur0 = 0, cur1 = 0, cur2 = 0, cur3 = 0;
    #pragma unroll
    for (int lvl = 0; lvl < DEPTH; ++lvl) {
        const int ca = 2 * cur0 + 1;
        const int cb = 2 * cur1 + 1;
        const int cc = 2 * cur2 + 1;
        const int cd = 2 * cur3 + 1;
        const float* pa = &nds[ca * RS + q4];
        const float* pb = &nds[cb * RS + q4];
        const float* pc = &nds[cc * RS + q4];
        const float* pd = &nds[cd * RS + q4];
        // issue all 8 reads; compiler batches them before one lgkmcnt wait
        const float4 A0 = *(const float4*)(pa);
        const float4 B0 = *(const float4*)(pa + RS);
        const float4 A1 = *(const float4*)(pb);
        const float4 B1 = *(const float4*)(pb + RS);
        const float4 A2 = *(const float4*)(pc);
        const float4 B2 = *(const float4*)(pc + RS);
        const float4 A3 = *(const float4*)(pd);
        const float4 B3 = *(const float4*)(pd + RS);

        float d, s0, s1;
        // chunk 0
        s0 = 0.f; s1 = 0.f;
        d = A0.x - xv0.x; s0 = fmaf(d, d, s0);  d = B0.x - xv0.x; s1 = fmaf(d, d, s1);
        d = A0.y - xv0.y; s0 = fmaf(d, d, s0);  d = B0.y - xv0.y; s1 = fmaf(d, d, s1);
        d = A0.z - xv0.z; s0 = fmaf(d, d, s0);  d = B0.z - xv0.z; s1 = fmaf(d, d, s1);
        d = A0.w - xv0.w; s0 = fmaf(d, d, s0);  d = B0.w - xv0.w; s1 = fmaf(d, d, s1);
        cur0 = (group16_sum(s1 - s0) < 0.0f) ? (ca + 1) : ca;   // d1<d0 picks c1 (strict)
        // chunk 1
        s0 = 0.f; s1 = 0.f;
        d = A1.x - xv1.x; s0 = fmaf(d, d, s0);  d = B1.x - xv1.x; s1 = fmaf(d, d, s1);
        d = A1.y - xv1.y; s0 = fmaf(d, d, s0);  d = B1.y - xv1.y; s1 = fmaf(d, d, s1);
        d = A1.z - xv1.z; s0 = fmaf(d, d, s0);  d = B1.z - xv1.z; s1 = fmaf(d, d, s1);
        d = A1.w - xv1.w; s0 = fmaf(d, d, s0);  d = B1.w - xv1.w; s1 = fmaf(d, d, s1);
        cur1 = (group16_sum(s1 - s0) < 0.0f) ? (cb + 1) : cb;
        // chunk 2
        s0 = 0.f; s1 = 0.f;
        d = A2.x - xv2.x; s0 = fmaf(d, d, s0);  d = B2.x - xv2.x; s1 = fmaf(d, d, s1);
        d = A2.y - xv2.y; s0 = fmaf(d, d, s0);  d = B2.y - xv2.y; s1 = fmaf(d, d, s1);
        d = A2.z - xv2.z; s0 = fmaf(d, d, s0);  d = B2.z - xv2.z; s1 = fmaf(d, d, s1);
        d = A2.w - xv2.w; s0 = fmaf(d, d, s0);  d = B2.w - xv2.w; s1 = fmaf(d, d, s1);
        cur2 = (group16_sum(s1 - s0) < 0.0f) ? (cc + 1) : cc;
        // chunk 3
        s0 = 0.f; s1 = 0.f;
        d = A3.x - xv3.x; s0 = fmaf(d, d, s0);  d = B3.x - xv3.x; s1 = fmaf(d, d, s1);
        d = A3.y - xv3.y; s0 = fmaf(d, d, s0);  d = B3.y - xv3.y; s1 = fmaf(d, d, s1);
        d = A3.z - xv3.z; s0 = fmaf(d, d, s0);  d = B3.z - xv3.z; s1 = fmaf(d, d, s1);
        d = A3.w - xv3.w; s0 = fmaf(d, d, s0);  d = B3.w - xv3.w; s1 = fmaf(d, d, s1);
        cur3 = (group16_sum(s1 - s0) < 0.0f) ? (cd + 1) : cd;
    }

    if (q == 0) {
        leaf_out[b * 256 + g]       = (float)cur0;
        leaf_out[b * 256 + 64 + g]  = (float)cur1;
        leaf_out[b * 256 + 128 + g] = (float)cur2;
        leaf_out[b * 256 + 192 + g] = (float)cur3;
        atomicAdd(&cntl[cur0 - 127], 1u);
        atomicAdd(&cntl[cur1 - 127], 1u);
        atomicAdd(&cntl[cur2 - 127], 1u);
        atomicAdd(&cntl[cur3 - 127], 1u);
    }

    // accumulate quads into leaf rows (R2-proven layout)
    {
        float* dst = &Sl[(cur0 - 127) * RS + q4];
        atomicAdd(dst + 0, xv0.x); atomicAdd(dst + 1, xv0.y);
        atomicAdd(dst + 2, xv0.z); atomicAdd(dst + 3, xv0.w);
        dst = &Sl[(cur1 - 127) * RS + q4];
        atomicAdd(dst + 0, xv1.x); atomicAdd(dst + 1, xv1.y);
        atomicAdd(dst + 2, xv1.z); atomicAdd(dst + 3, xv1.w);
        dst = &Sl[(cur2 - 127) * RS + q4];
        atomicAdd(dst + 0, xv2.x); atomicAdd(dst + 1, xv2.y);
        atomicAdd(dst + 2, xv2.z); atomicAdd(dst + 3, xv2.w);
        dst = &Sl[(cur3 - 127) * RS + q4];
        atomicAdd(dst + 0, xv3.x); atomicAdd(dst + 1, xv3.y);
        atomicAdd(dst + 2, xv3.z); atomicAdd(dst + 3, xv3.w);
    }
    __syncthreads();

    // flush block sums to global S (skip zeros; lane-distinct addresses; S pre-zeroed)
    for (int i = t; i < NLEAF * 64; i += 1024) {
        const float v = Sl[(i >> 6) * RS + (i & 63)];
        if (v != 0.0f) atomicAdd(&S[i], v);
    }
    if (t < NLEAF && cntl[t] != 0u) atomicAdd(&cnt[t], cntl[t]);

    // ---- arrival + fused node update, ONE node per block --------------------
    __syncthreads();   // barrier drains vmcnt -> this block's atomics complete
    if (t == 0) {
        __threadfence();
        __hip_atomic_fetch_add(fdone, 1u, __ATOMIC_RELEASE, __HIP_MEMORY_SCOPE_AGENT);
    }
    if (b >= NUM_NODES) return;   // block 255 has no node; 255 blocks continue

    // only wave 0 polls (255 polling waves chip-wide, s_sleep backoff);
    // waves 1..15 park at the hardware barrier below (zero fabric traffic).
    if (t < 64) {
        while (__hip_atomic_load(fdone, __ATOMIC_ACQUIRE, __HIP_MEMORY_SCOPE_AGENT) != NBLK) {
            __builtin_amdgcn_s_sleep(2);
        }
    }
    __syncthreads();

    // stage S (32KB) + cnt into reused LDS via agent-scope loads (coherent point);
    // 1024 threads x 8 coalesced loads.
    float* Ss = nds;            // 8192 floats
    float* cs = nds + 8192;     // 128 floats
    for (int i = t; i < NLEAF * 64; i += 1024)
        Ss[i] = __hip_atomic_load(&S[i], __ATOMIC_RELAXED, __HIP_MEMORY_SCOPE_AGENT);
    if (t < NLEAF)
        cs[t] = (float)__hip_atomic_load(&cnt[t], __ATOMIC_RELAXED, __HIP_MEMORY_SCOPE_AGENT);
    __syncthreads();

    // node n = b, one output element per lane of wave 0 (Ss[L*64+k], k=0..63
    // consecutive -> conflict-free broadcast-ish reads)
    if (t < 64) {
        const int n = b;
        const int k = t;
        const float nd = nodes[n * 64 + k];
        float o;
        if (n == 0) {
            o = nd;
        } else {
            const int pos = n + 1;                 // 1-based heap index
            const int Ln = 31 - __clz(pos);        // node level, 1..7
            float su = 0.f, sc = 0.f;
            #pragma unroll 8
            for (int L = 0; L < NLEAF; ++L) {
                const int a = (128 + L) >> (7 - Ln);   // leaf's ancestor at level Ln
                const int x = pos ^ a;
                const int state = (x == 0) ? Ln : (Ln - (31 - __clz(x)) - 1);
                const float lr = 0.3f * ((float)(1 << state) * (1.0f / 128.0f));
                su = fmaf(lr, Ss[L * 64 + k], su);
                sc = fmaf(lr, cs[L], sc);
            }
            const float invP = 1.0f / 65536.0f;
            o = nd + su * invP - (sc * invP) * nd;
        }
        out_nodes[n * 64 + k] = o;
    }
}

extern "C" void kernel_launch(void* const* d_in, const int* in_sizes, int n_in,
                              void* d_out, int out_size, void* d_ws, size_t ws_size,
                              hipStream_t stream)
{
    const float* img   = (const float*)d_in[0];   // 2048*2048 f32
    const float* nodes = (const float*)d_in[1];   // 255*64 f32

    float* out_nodes = (float*)d_out;                 // 255*64
    float* out_leaf  = out_nodes + NUM_NODES * 64;    // 65536 (leaf index as f32)

    float*    S     = (float*)d_ws;                   // 128*64 f32
    unsigned* cnt   = (unsigned*)(S + NLEAF * 64);    // 128 u32
    unsigned* fdone = cnt + NLEAF;                    // 1 u32 arrival counter

    hipMemsetAsync(d_ws, 0,
                   (NLEAF * 64) * sizeof(float) + NLEAF * sizeof(unsigned) + 16,
                   stream);
    fusedK<<<NBLK, 1024, 0, stream>>>(img, nodes, out_leaf, S, cnt, fdone, out_nodes);
}

// Round 7
// 105.974 us; speedup vs baseline: 1.1379x; 1.1379x over previous
//
#include <hip/hip_runtime.h>

#define IMG_W 2048
#define NUM_NODES 255
#define NLEAF 128
#define DEPTH 7
#define RS 68   // padded LDS row stride (floats); 16B-chunk bank-group = (row+q)%8 -> balanced

// DPP xor-butterfly add over 16-lane groups (VALU pipe). Butterfly partners add
// identical pairs -> all 16 lanes end bit-identical.
template<int CTRL>
__device__ __forceinline__ float dpp_add(float x) {
    int v = __builtin_amdgcn_update_dpp(0, __float_as_int(x), CTRL, 0xF, 0xF, true);
    return x + __int_as_float(v);
}
__device__ __forceinline__ float group16_sum(float x) {
    x = dpp_add<0xB1>(x);   // quad_perm [1,0,3,2]  : xor 1
    x = dpp_add<0x4E>(x);   // quad_perm [2,3,0,1]  : xor 2
    x = dpp_add<0x141>(x);  // row_half_mirror      : xor 7
    x = dpp_add<0x128>(x);  // row_ror:8            : xor 8
    return x;
}

// ---- K1: 4-way interleaved descent (16 lanes/patch) + LDS-atomic accumulate --
// 256 blocks x 1024 thr, ~105 KB LDS -> 1 block/CU, 16 waves/CU.
// SESSION LEDGER (R0-R6): this is the converged structure.
//  - R1 slice+reduce (no global atomics): +8us  -> atomic flush is cheap, keep.
//  - R3 fusion (16-CU tail):              +10us -> reverted.
//  - R4 accumulate transpose:             +0.8us, conflicts UP (682K) -> reverted.
//  - R5 reg-cached levels 0-1:            +1.7us (conflicts down but neutral
//    -> descent LDS pipe is not the limiter) -> reverted.
//  - R6 fusion (1 node/block, spin):      +15us (steady fusedK 64us: scalar
//    agent-scope S staging + global spin) -> reverted.
// Steady-state budget: 86us = 2x harness 256MiB poison fills (fixed);
// fusedK ~13us (latency/structure bound), updateK ~2.5, memset ~2, gaps ~3.
__global__ __launch_bounds__(1024, 4) void fusedK(const float* __restrict__ img,
                                                  const float* __restrict__ nodes,
                                                  float* __restrict__ leaf_out,
                                                  float* __restrict__ S,
                                                  unsigned* __restrict__ cnt)
{
    __shared__ float nds[NUM_NODES * RS];   // 69360 B
    __shared__ float Sl[NLEAF * RS];        // 34816 B
    __shared__ unsigned cntl[NLEAF];

    const int t = threadIdx.x;
    const int b = blockIdx.x;
    const int g = t >> 4;          // patch-group 0..63
    const int q = t & 15;          // quad within patch (elements 4q..4q+3)
    const int q4 = q * 4;

    for (int i = t; i < NLEAF * RS; i += 1024) Sl[i] = 0.0f;
    if (t < NLEAF) cntl[t] = 0u;

    // fill node table (padded rows)
    const float4* ng = (const float4*)nodes;
    for (int i = t; i < NUM_NODES * 16; i += 1024) {
        *(float4*)&nds[(i >> 4) * RS + (i & 15) * 4] = ng[i];
    }

    // prefetch 4 chunks' patch quads (element e=4q+j -> pixel (q>>1, (q&1)*4+j))
    float4 xv0, xv1, xv2, xv3;
    {
        const int roff = (q >> 1), coff = (q & 1) * 4;
        int p = b * 256 + g;
        xv0 = *(const float4*)(img + (size_t)((p >> 8) * 8 + roff) * IMG_W + (p & 255) * 8 + coff);
        p += 64;
        xv1 = *(const float4*)(img + (size_t)((p >> 8) * 8 + roff) * IMG_W + (p & 255) * 8 + coff);
        p += 64;
        xv2 = *(const float4*)(img + (size_t)((p >> 8) * 8 + roff) * IMG_W + (p & 255) * 8 + coff);
        p += 64;
        xv3 = *(const float4*)(img + (size_t)((p >> 8) * 8 + roff) * IMG_W + (p & 255) * 8 + coff);
    }
    __syncthreads();

    // 4 interleaved descents
    int cur0 = 0, cur1 = 0, cur2 = 0, cur3 = 0;
    #pragma unroll
    for (int lvl = 0; lvl < DEPTH; ++lvl) {
        const int ca = 2 * cur0 + 1;
        const int cb = 2 * cur1 + 1;
        const int cc = 2 * cur2 + 1;
        const int cd = 2 * cur3 + 1;
        const float* pa = &nds[ca * RS + q4];
        const float* pb = &nds[cb * RS + q4];
        const float* pc = &nds[cc * RS + q4];
        const float* pd = &nds[cd * RS + q4];
        // issue all 8 reads; compiler batches them before one lgkmcnt wait
        const float4 A0 = *(const float4*)(pa);
        const float4 B0 = *(const float4*)(pa + RS);
        const float4 A1 = *(const float4*)(pb);
        const float4 B1 = *(const float4*)(pb + RS);
        const float4 A2 = *(const float4*)(pc);
        const float4 B2 = *(const float4*)(pc + RS);
        const float4 A3 = *(const float4*)(pd);
        const float4 B3 = *(const float4*)(pd + RS);

        float d, s0, s1;
        // chunk 0
        s0 = 0.f; s1 = 0.f;
        d = A0.x - xv0.x; s0 = fmaf(d, d, s0);  d = B0.x - xv0.x; s1 = fmaf(d, d, s1);
        d = A0.y - xv0.y; s0 = fmaf(d, d, s0);  d = B0.y - xv0.y; s1 = fmaf(d, d, s1);
        d = A0.z - xv0.z; s0 = fmaf(d, d, s0);  d = B0.z - xv0.z; s1 = fmaf(d, d, s1);
        d = A0.w - xv0.w; s0 = fmaf(d, d, s0);  d = B0.w - xv0.w; s1 = fmaf(d, d, s1);
        cur0 = (group16_sum(s1 - s0) < 0.0f) ? (ca + 1) : ca;   // d1<d0 picks c1 (strict)
        // chunk 1
        s0 = 0.f; s1 = 0.f;
        d = A1.x - xv1.x; s0 = fmaf(d, d, s0);  d = B1.x - xv1.x; s1 = fmaf(d, d, s1);
        d = A1.y - xv1.y; s0 = fmaf(d, d, s0);  d = B1.y - xv1.y; s1 = fmaf(d, d, s1);
        d = A1.z - xv1.z; s0 = fmaf(d, d, s0);  d = B1.z - xv1.z; s1 = fmaf(d, d, s1);
        d = A1.w - xv1.w; s0 = fmaf(d, d, s0);  d = B1.w - xv1.w; s1 = fmaf(d, d, s1);
        cur1 = (group16_sum(s1 - s0) < 0.0f) ? (cb + 1) : cb;
        // chunk 2
        s0 = 0.f; s1 = 0.f;
        d = A2.x - xv2.x; s0 = fmaf(d, d, s0);  d = B2.x - xv2.x; s1 = fmaf(d, d, s1);
        d = A2.y - xv2.y; s0 = fmaf(d, d, s0);  d = B2.y - xv2.y; s1 = fmaf(d, d, s1);
        d = A2.z - xv2.z; s0 = fmaf(d, d, s0);  d = B2.z - xv2.z; s1 = fmaf(d, d, s1);
        d = A2.w - xv2.w; s0 = fmaf(d, d, s0);  d = B2.w - xv2.w; s1 = fmaf(d, d, s1);
        cur2 = (group16_sum(s1 - s0) < 0.0f) ? (cc + 1) : cc;
        // chunk 3
        s0 = 0.f; s1 = 0.f;
        d = A3.x - xv3.x; s0 = fmaf(d, d, s0);  d = B3.x - xv3.x; s1 = fmaf(d, d, s1);
        d = A3.y - xv3.y; s0 = fmaf(d, d, s0);  d = B3.y - xv3.y; s1 = fmaf(d, d, s1);
        d = A3.z - xv3.z; s0 = fmaf(d, d, s0);  d = B3.z - xv3.z; s1 = fmaf(d, d, s1);
        d = A3.w - xv3.w; s0 = fmaf(d, d, s0);  d = B3.w - xv3.w; s1 = fmaf(d, d, s1);
        cur3 = (group16_sum(s1 - s0) < 0.0f) ? (cd + 1) : cd;
    }

    if (q == 0) {
        leaf_out[b * 256 + g]       = (float)cur0;
        leaf_out[b * 256 + 64 + g]  = (float)cur1;
        leaf_out[b * 256 + 128 + g] = (float)cur2;
        leaf_out[b * 256 + 192 + g] = (float)cur3;
        atomicAdd(&cntl[cur0 - 127], 1u);
        atomicAdd(&cntl[cur1 - 127], 1u);
        atomicAdd(&cntl[cur2 - 127], 1u);
        atomicAdd(&cntl[cur3 - 127], 1u);
    }

    // accumulate quads into leaf rows
    {
        float* dst = &Sl[(cur0 - 127) * RS + q4];
        atomicAdd(dst + 0, xv0.x); atomicAdd(dst + 1, xv0.y);
        atomicAdd(dst + 2, xv0.z); atomicAdd(dst + 3, xv0.w);
        dst = &Sl[(cur1 - 127) * RS + q4];
        atomicAdd(dst + 0, xv1.x); atomicAdd(dst + 1, xv1.y);
        atomicAdd(dst + 2, xv1.z); atomicAdd(dst + 3, xv1.w);
        dst = &Sl[(cur2 - 127) * RS + q4];
        atomicAdd(dst + 0, xv2.x); atomicAdd(dst + 1, xv2.y);
        atomicAdd(dst + 2, xv2.z); atomicAdd(dst + 3, xv2.w);
        dst = &Sl[(cur3 - 127) * RS + q4];
        atomicAdd(dst + 0, xv3.x); atomicAdd(dst + 1, xv3.y);
        atomicAdd(dst + 2, xv3.z); atomicAdd(dst + 3, xv3.w);
    }
    __syncthreads();

    // flush block sums to global S (skip zeros; lane-distinct addresses; S pre-zeroed)
    for (int i = t; i < NLEAF * 64; i += 1024) {
        const float v = Sl[(i >> 6) * RS + (i & 63)];
        if (v != 0.0f) atomicAdd(&S[i], v);
    }
    if (t < NLEAF && cntl[t] != 0u) atomicAdd(&cnt[t], cntl[t]);
}

// ---------------- K2: node update (254x64x128 contraction) -------------------
// R2-proven: stage S (32KB) + cnt into LDS once per block; the leaf loop
// otherwise issues ~4.2M stride-256B global loads (latency-bound at low occ).
__global__ __launch_bounds__(256) void updateK(const float* __restrict__ nodes,
                                               const float* __restrict__ S,
                                               const unsigned* __restrict__ cnt,
                                               float* __restrict__ out)
{
    __shared__ float Ss[NLEAF * 64];    // 32768 B
    __shared__ float cs[NLEAF];

    const int t = threadIdx.x;
    // stage S: 2048 float4 over 256 threads = 8 each, coalesced
    #pragma unroll
    for (int i = t; i < NLEAF * 16; i += 256) {
        ((float4*)Ss)[i] = ((const float4*)S)[i];
    }
    if (t < NLEAF) cs[t] = (float)cnt[t];
    __syncthreads();

    const int gid = blockIdx.x * 256 + t;
    if (gid >= NUM_NODES * 64) return;
    const int n = gid >> 6, k = gid & 63;
    const float nd = nodes[gid];
    if (n == 0) { out[gid] = nd; return; }

    const int pos = n + 1;                 // 1-based heap index
    const int Ln = 31 - __clz(pos);        // node level, 1..7
    float su = 0.f, sc = 0.f;
    #pragma unroll 8
    for (int L = 0; L < NLEAF; ++L) {
        const int a = (128 + L) >> (7 - Ln);   // leaf's ancestor at level Ln
        const int x = pos ^ a;
        const int state = (x == 0) ? Ln : (Ln - (31 - __clz(x)) - 1);
        const float lr = 0.3f * ((float)(1 << state) * (1.0f / 128.0f));
        su = fmaf(lr, Ss[L * 64 + k], su);
        sc = fmaf(lr, cs[L], sc);
    }
    const float invP = 1.0f / 65536.0f;
    out[gid] = nd + su * invP - (sc * invP) * nd;
}

extern "C" void kernel_launch(void* const* d_in, const int* in_sizes, int n_in,
                              void* d_out, int out_size, void* d_ws, size_t ws_size,
                              hipStream_t stream)
{
    const float* img   = (const float*)d_in[0];   // 2048*2048 f32
    const float* nodes = (const float*)d_in[1];   // 255*64 f32

    float* out_nodes = (float*)d_out;                 // 255*64
    float* out_leaf  = out_nodes + NUM_NODES * 64;    // 65536 (leaf index as f32)

    float*    S   = (float*)d_ws;                     // 128*64 f32
    unsigned* cnt = (unsigned*)(S + NLEAF * 64);      // 128 u32

    hipMemsetAsync(d_ws, 0, (NLEAF * 64) * sizeof(float) + NLEAF * sizeof(unsigned), stream);
    fusedK<<<256, 1024, 0, stream>>>(img, nodes, out_leaf, S, cnt);
    updateK<<<64, 256, 0, stream>>>(nodes, S, cnt, out_nodes);
}